// Round 1
// baseline (103.714 us; speedup 1.0000x reference)
//
#include <hip/hip_runtime.h>

#define IW 512
#define IH 512
#define NPLANES 48            // 16 batch * 3 channels
#define BLOCK 256             // 4 waves per block
#define ROWS 4                // output rows per wave (rolling window)

typedef float v4f __attribute__((ext_vector_type(4)));

__device__ __forceinline__ float med3f(float a, float b, float c) {
    return __builtin_amdgcn_fmed3f(a, b, c);
}
__device__ __forceinline__ float max3f(float a, float b, float c) {
    return fmaxf(fmaxf(a, b), c);   // fuses to v_max3_f32
}
__device__ __forceinline__ float min3f(float a, float b, float c) {
    return fminf(fminf(a, b), c);   // fuses to v_min3_f32
}

__device__ __forceinline__ void load8(const float* __restrict__ r, float* d) {
    v4f a = *(const v4f*)(r);
    v4f b = *(const v4f*)(r + 4);
    d[0] = a.x; d[1] = a.y; d[2] = a.z; d[3] = a.w;
    d[4] = b.x; d[5] = b.y; d[6] = b.z; d[7] = b.w;
}

// One wave (64 lanes) processes ROWS consecutive image rows of one plane;
// each lane owns 8 columns. Vertical triples come from a rolling 3-row
// register window (each input row loaded once per wave instead of 3x).
__global__ __launch_bounds__(BLOCK) void median3x3_kernel(
    const float* __restrict__ x, float* __restrict__ out) {
    int tid  = blockIdx.x * BLOCK + threadIdx.x;
    int lane = threadIdx.x & 63;
    int w    = tid >> 6;                  // global wave id = row-group id
    int g    = w & (IH / ROWS - 1);       // row-group within plane (128 = 2^7)
    int p    = w >> 7;                    // plane id
    int y0   = g * ROWS;                  // first output row of this wave
    int x0   = lane << 3;                 // first of 8 columns owned by lane

    const float* plane = x   + (size_t)p * IH * IW;
    float*       dpl   = out + (size_t)p * IH * IW;

    // rolling rows: a = row y-1, b = row y, c = row y+1 (reflect at edges)
    float a[8], b[8], c[8];
    int ym = (y0 == 0) ? 1 : y0 - 1;
    load8(plane + (size_t)ym * IW + x0, a);
    load8(plane + (size_t)y0 * IW + x0, b);

#pragma unroll
    for (int r = 0; r < ROWS; r++) {
        int y  = y0 + r;
        int yn = (y == IH - 1) ? IH - 2 : y + 1;   // reflect bottom edge
        load8(plane + (size_t)yn * IW + x0, c);

        // vertical order statistics per owned column: 3 VOP3 ops each
        float lo[10], mi[10], hi[10];   // [0]=left halo, [1..8]=own, [9]=right halo
#pragma unroll
        for (int k = 0; k < 8; k++) {
            lo[k + 1] = min3f(a[k], b[k], c[k]);
            mi[k + 1] = med3f(a[k], b[k], c[k]);
            hi[k + 1] = max3f(a[k], b[k], c[k]);
        }

        // halo exchange of SORTED triples via wave shuffles
        float Ll = __shfl_up(lo[8], 1, 64);
        float Lm = __shfl_up(mi[8], 1, 64);
        float Lh = __shfl_up(hi[8], 1, 64);
        float Rl = __shfl_down(lo[1], 1, 64);
        float Rm = __shfl_down(mi[1], 1, 64);
        float Rh = __shfl_down(hi[1], 1, 64);
        if (lane == 0)  { Ll = lo[2]; Lm = mi[2]; Lh = hi[2]; }  // reflect col -1 -> 1
        if (lane == 63) { Rl = lo[7]; Rm = mi[7]; Rh = hi[7]; }  // reflect 512 -> 510
        lo[0] = Ll; mi[0] = Lm; hi[0] = Lh;
        lo[9] = Rl; mi[9] = Rm; hi[9] = Rh;

        // horizontal merge: median9 = med3(max3(lo), med3(mi), min3(hi))
        float o[8];
#pragma unroll
        for (int j = 0; j < 8; j++) {
            float M = max3f(lo[j], lo[j + 1], lo[j + 2]);
            float m = med3f(mi[j], mi[j + 1], mi[j + 2]);
            float n = min3f(hi[j], hi[j + 1], hi[j + 2]);
            o[j] = med3f(M, m, n);
        }

        float* dst = dpl + (size_t)y * IW + x0;
        v4f r0 = {o[0], o[1], o[2], o[3]};
        v4f r1 = {o[4], o[5], o[6], o[7]};
        __builtin_nontemporal_store(r0, (v4f*)dst);
        __builtin_nontemporal_store(r1, (v4f*)(dst + 4));

        // roll the window (register-renamed by full unroll, no v_mov cost)
#pragma unroll
        for (int k = 0; k < 8; k++) { a[k] = b[k]; b[k] = c[k]; }
    }
}

extern "C" void kernel_launch(void* const* d_in, const int* in_sizes, int n_in,
                              void* d_out, int out_size, void* d_ws, size_t ws_size,
                              hipStream_t stream) {
    const float* x = (const float*)d_in[0];
    float* out = (float*)d_out;
    // waves = 48 planes * 128 row-groups = 6144 ; threads = 6144*64 = 393216
    int total  = NPLANES * (IH / ROWS) * 64;
    int blocks = total / BLOCK;   // 1536
    median3x3_kernel<<<blocks, BLOCK, 0, stream>>>(x, out);
}